// Round 2
// baseline (10492.019 us; speedup 1.0000x reference)
//
#include <hip/hip_runtime.h>
#include <math.h>

#define N_NODES 100000
#define N_EDGES 1600000

__device__ __forceinline__ float bcast(float v, int srclane) {
    return __uint_as_float(__builtin_amdgcn_readlane(__float_as_uint(v), srclane));
}

// ---------------------------------------------------------------------------
// Node projections: Q,K,V,G = x @ W.T (+bias for G). One node per lane,
// weights read as wave-uniform scalars (s_load), x row in registers.
// ---------------------------------------------------------------------------
__global__ __launch_bounds__(256) void k_node_proj(
    const float* __restrict__ x,
    const float* __restrict__ WQ, const float* __restrict__ WK,
    const float* __restrict__ WV, const float* __restrict__ NG,
    const float* __restrict__ NGb,
    float* __restrict__ Qout, float* __restrict__ SRCout)
{
    int n = blockIdx.x * 256 + threadIdx.x;
    if (n >= N_NODES) return;

    float xr[64];
    const float4* xp = reinterpret_cast<const float4*>(x + (size_t)n * 64);
#pragma unroll
    for (int i = 0; i < 16; ++i) {
        float4 v = xp[i];
        xr[4*i+0] = v.x; xr[4*i+1] = v.y; xr[4*i+2] = v.z; xr[4*i+3] = v.w;
    }

    float4* qo = reinterpret_cast<float4*>(Qout + (size_t)n * 64);
    float4* so = reinterpret_cast<float4*>(SRCout + (size_t)n * 192);

    for (int o4 = 0; o4 < 16; ++o4) {
        float q[4] = {0.f,0.f,0.f,0.f};
        float k[4] = {0.f,0.f,0.f,0.f};
        float v[4] = {0.f,0.f,0.f,0.f};
        float g[4];
#pragma unroll
        for (int s = 0; s < 4; ++s) g[s] = NGb[o4*4+s];
#pragma unroll
        for (int j = 0; j < 64; ++j) {
            float xj = xr[j];
#pragma unroll
            for (int s = 0; s < 4; ++s) {
                int row = o4*4 + s;
                q[s] = fmaf(WQ[row*64+j], xj, q[s]);
                k[s] = fmaf(WK[row*64+j], xj, k[s]);
                v[s] = fmaf(WV[row*64+j], xj, v[s]);
                g[s] = fmaf(NG[row*64+j], xj, g[s]);
            }
        }
        qo[o4]      = make_float4(q[0], q[1], q[2], q[3]);
        so[o4]      = make_float4(k[0], k[1], k[2], k[3]);   // K @ [0,64)
        so[16+o4]   = make_float4(v[0], v[1], v[2], v[3]);   // V @ [64,128)
        so[32+o4]   = make_float4(g[0], g[1], g[2], g[3]);   // G @ [128,192)
    }
}

// ---------------------------------------------------------------------------
// Prep: transpose WO, ffn_w1, ffn_w2 (64x64) for node-final.
// ---------------------------------------------------------------------------
__global__ void k_transpose3(const float* __restrict__ A,
                             const float* __restrict__ B,
                             const float* __restrict__ C,
                             float* __restrict__ T)
{
    int m = blockIdx.x;
    const float* W = (m == 0) ? A : ((m == 1) ? B : C);
    float* O = T + (size_t)m * 4096;
    for (int k = threadIdx.x; k < 4096; k += 256) {
        int j = k >> 6, o = k & 63;
        O[k] = W[o*64 + j];
    }
}

// ---------------------------------------------------------------------------
// Fused edge pass, WAVE-PER-EDGE (lane = feature dim).
//   - coalesced gathers of Q[dst], K/V/G[src]
//   - Ef/Eg GEMVs: per-lane weight columns in VGPRs, ea broadcast via readlane
//   - logit reduce within 16-lane head groups, ex = exp(logit)
//   - coalesced atomics: agg (64 lanes -> 2 lines), sden (4 lanes -> 1 line)
//   - edge update (WOe/FFN weights transposed in LDS, broadcasts via readlane)
// Persistent grid-stride so weight setup is amortized.
// ---------------------------------------------------------------------------
__global__ __launch_bounds__(256, 4) void k_edge_fused(
    const float* __restrict__ ea_g,
    const int*   __restrict__ ei,
    const float* __restrict__ Q,   const float* __restrict__ SRC,
    const float* __restrict__ WE,  const float* __restrict__ WEb,
    const float* __restrict__ EG,  const float* __restrict__ EGb,
    const float* __restrict__ WOe, const float* __restrict__ WOeb,
    const float* __restrict__ W1,  const float* __restrict__ W1b,
    const float* __restrict__ W2,  const float* __restrict__ W2b,
    const float* __restrict__ g1,  const float* __restrict__ b1,
    const float* __restrict__ g2,  const float* __restrict__ b2,
    float* __restrict__ sden, float* __restrict__ agg,
    float* __restrict__ eout)
{
    __shared__ float sWOT[64*32];   // sWOT[k][j] = WOe[j][k]
    __shared__ float sW1T[32*64];   // sW1T[j][k] = W1[k][j]
    __shared__ float sW2T[64*32];   // sW2T[k][j] = W2[j][k]

    const int tid  = threadIdx.x;
    const int wid  = tid >> 6;
    const int lane = tid & 63;
    const int j32  = lane & 31;

    for (int i = tid; i < 2048; i += 256) {
        int k = i >> 5, j = i & 31;
        sWOT[i] = WOe[j*64 + k];
        sW2T[i] = W2[j*64 + k];
    }
    for (int i = tid; i < 2048; i += 256) {
        int j = i >> 6, k = i & 63;
        sW1T[i] = W1[k*32 + j];
    }
    __syncthreads();

    // per-lane hoisted weights (Ef/Eg columns) and params
    float wet[32], egt[32];
    {
        const float4* wp = reinterpret_cast<const float4*>(WE + (size_t)lane * 32);
        const float4* gp = reinterpret_cast<const float4*>(EG + (size_t)lane * 32);
#pragma unroll
        for (int i = 0; i < 8; ++i) {
            float4 a = wp[i];
            wet[4*i+0]=a.x; wet[4*i+1]=a.y; wet[4*i+2]=a.z; wet[4*i+3]=a.w;
            float4 b = gp[i];
            egt[4*i+0]=b.x; egt[4*i+1]=b.y; egt[4*i+2]=b.z; egt[4*i+3]=b.w;
        }
    }
    const float wEb_r  = WEb[lane];
    const float eGb_r  = EGb[lane];
    const float w1b_r  = W1b[lane];
    const float wOeb_r = WOeb[j32];
    const float w2b_r  = W2b[j32];
    const float g1_r   = g1[j32];
    const float b1_r   = b1[j32];
    const float g2_r   = g2[j32];
    const float b2_r   = b2[j32];

    const int stride = gridDim.x * 4;
    for (int e = blockIdx.x * 4 + wid; e < N_EDGES; e += stride) {
        const int eu  = __builtin_amdgcn_readfirstlane(e);
        const int src = ei[eu];
        const int dst = ei[N_EDGES + eu];

        const float eav = ea_g[(size_t)eu*32 + j32];
        const float qd  = Q[(size_t)dst*64 + lane];
        const float ks  = SRC[(size_t)src*192 + lane];
        const float vsv = SRC[(size_t)src*192 + 64 + lane];
        const float gsv = SRC[(size_t)src*192 + 128 + lane];

        // Ef, Eg GEMVs (32 -> 64), ea broadcast via readlane (SGPR operand)
        float ef = wEb_r, eg = eGb_r;
#pragma unroll
        for (int j = 0; j < 32; ++j) {
            float b = bcast(eav, j);
            ef = fmaf(wet[j], b, ef);
            eg = fmaf(egt[j], b, eg);
        }

        // eij[d] = Q*K*Ef/4
        const float t = qd * ks * ef * 0.25f;

        // logit = per-head sum over 16 lanes
        float lg = t;
        lg += __shfl_xor(lg, 1);
        lg += __shfl_xor(lg, 2);
        lg += __shfl_xor(lg, 4);
        lg += __shfl_xor(lg, 8);
        const float ex = __expf(lg);

        if ((lane & 15) == 0)
            atomicAdd(&sden[(size_t)dst*4 + (lane >> 4)], ex);

        // gated value message (coalesced atomic: 64 lanes -> 2 lines)
        const float gate = 1.f / (1.f + __expf(-(gsv + eg)));
        atomicAdd(&agg[(size_t)dst*64 + lane], ex * gate * vsv);

        // ---- edge update: WOe GEMV (both halves duplicate j32 output) ----
        float emid = 0.f;
#pragma unroll
        for (int k = 0; k < 64; ++k)
            emid = fmaf(sWOT[k*32 + j32], bcast(t, k), emid);

        // LN1 over 32 dims (halves hold duplicates; xor<32 stays in half)
        float y = emid + wOeb_r + eav;
        {
            float s = y;
            s += __shfl_xor(s, 1); s += __shfl_xor(s, 2);
            s += __shfl_xor(s, 4); s += __shfl_xor(s, 8); s += __shfl_xor(s, 16);
            float mean = s * (1.f/32.f);
            float d = y - mean;
            float v = d*d;
            v += __shfl_xor(v, 1); v += __shfl_xor(v, 2);
            v += __shfl_xor(v, 4); v += __shfl_xor(v, 8); v += __shfl_xor(v, 16);
            float rs = rsqrtf(v*(1.f/32.f) + 1e-5f);
            y = d*rs*g1_r + b1_r;
        }

        // FFN: h[lane] = relu(W1 @ y + b1)
        float h = w1b_r;
#pragma unroll
        for (int j = 0; j < 32; ++j)
            h = fmaf(sW1T[j*64 + lane], bcast(y, j), h);
        h = fmaxf(h, 0.f);

        // ff[j32] = W2 @ h + b2, + residual y
        float f2 = 0.f;
#pragma unroll
        for (int k = 0; k < 64; ++k)
            f2 = fmaf(sW2T[k*32 + j32], bcast(h, k), f2);
        f2 += w2b_r + y;

        // LN2
        {
            float s = f2;
            s += __shfl_xor(s, 1); s += __shfl_xor(s, 2);
            s += __shfl_xor(s, 4); s += __shfl_xor(s, 8); s += __shfl_xor(s, 16);
            float mean = s * (1.f/32.f);
            float d = f2 - mean;
            float v = d*d;
            v += __shfl_xor(v, 1); v += __shfl_xor(v, 2);
            v += __shfl_xor(v, 4); v += __shfl_xor(v, 8); v += __shfl_xor(v, 16);
            float rs = rsqrtf(v*(1.f/32.f) + 1e-5f);
            f2 = d*rs*g2_r + b2_r;
        }

        if (lane < 32)
            eout[(size_t)eu*32 + lane] = f2;
    }
}

// ---------------------------------------------------------------------------
// Node finalization: wave per node (unchanged).
// ---------------------------------------------------------------------------
__global__ __launch_bounds__(256) void k_node_final(
    const float* __restrict__ agg, const float* __restrict__ sden,
    const float* __restrict__ x,
    const float* __restrict__ WOT, const float* __restrict__ WOb,
    const float* __restrict__ W1T, const float* __restrict__ W1b,
    const float* __restrict__ W2T, const float* __restrict__ W2b,
    const float* __restrict__ g1,  const float* __restrict__ b1,
    const float* __restrict__ g2,  const float* __restrict__ b2,
    float* __restrict__ outp)
{
    int gid  = blockIdx.x * 256 + threadIdx.x;
    int n    = gid >> 6;
    int lane = threadIdx.x & 63;
    if (n >= N_NODES) return;

    float a = agg[(size_t)n*64 + lane] / (sden[(size_t)n*4 + (lane>>4)] + 1e-16f);

    float acc = WOb[lane] + x[(size_t)n*64 + lane];
    for (int j = 0; j < 64; ++j)
        acc = fmaf(WOT[j*64 + lane], __shfl(a, j), acc);

    float s = acc;
    for (int off = 32; off; off >>= 1) s += __shfl_xor(s, off);
    float mean = s * (1.f/64.f);
    float d = acc - mean;
    float vs = d*d;
    for (int off = 32; off; off >>= 1) vs += __shfl_xor(vs, off);
    float rs = rsqrtf(vs*(1.f/64.f) + 1e-5f);
    float yv = d*rs*g1[lane] + b1[lane];

    float hk = W1b[lane];
    for (int j = 0; j < 64; ++j)
        hk = fmaf(W1T[j*64 + lane], __shfl(yv, j), hk);
    hk = fmaxf(hk, 0.f);
    float fo = W2b[lane];
    for (int k = 0; k < 64; ++k)
        fo = fmaf(W2T[k*64 + lane], __shfl(hk, k), fo);

    float u = yv + fo;
    float s2 = u;
    for (int off = 32; off; off >>= 1) s2 += __shfl_xor(s2, off);
    float mean2 = s2 * (1.f/64.f);
    float d2 = u - mean2;
    float v2 = d2*d2;
    for (int off = 32; off; off >>= 1) v2 += __shfl_xor(v2, off);
    float rs2 = rsqrtf(v2*(1.f/64.f) + 1e-5f);

    outp[(size_t)n*64 + lane] = d2*rs2*g2[lane] + b2[lane];
}

// ---------------------------------------------------------------------------
extern "C" void kernel_launch(void* const* d_in, const int* in_sizes, int n_in,
                              void* d_out, int out_size, void* d_ws, size_t ws_size,
                              hipStream_t stream)
{
    const float* x    = (const float*)d_in[0];
    const float* ea   = (const float*)d_in[1];
    const float* WQ   = (const float*)d_in[2];
    const float* WK   = (const float*)d_in[3];
    const float* WV   = (const float*)d_in[4];
    const float* WO   = (const float*)d_in[5];
    const float* WOb  = (const float*)d_in[6];
    const float* WE   = (const float*)d_in[7];
    const float* WEb  = (const float*)d_in[8];
    const float* WOe  = (const float*)d_in[9];
    const float* WOeb = (const float*)d_in[10];
    const float* NG   = (const float*)d_in[11];
    const float* NGb  = (const float*)d_in[12];
    const float* EGw  = (const float*)d_in[13];
    const float* EGb  = (const float*)d_in[14];
    const float* F1   = (const float*)d_in[15];
    const float* F1b  = (const float*)d_in[16];
    const float* F2   = (const float*)d_in[17];
    const float* F2b  = (const float*)d_in[18];
    const float* FE1  = (const float*)d_in[19];
    const float* FE1b = (const float*)d_in[20];
    const float* FE2  = (const float*)d_in[21];
    const float* FE2b = (const float*)d_in[22];
    const float* n1g  = (const float*)d_in[23];
    const float* n1b  = (const float*)d_in[24];
    const float* n2g  = (const float*)d_in[25];
    const float* n2b  = (const float*)d_in[26];
    const float* n1eg = (const float*)d_in[27];
    const float* n1eb = (const float*)d_in[28];
    const float* n2eg = (const float*)d_in[29];
    const float* n2eb = (const float*)d_in[30];
    const int*   ei   = (const int*)d_in[31];

    float* ws   = (float*)d_ws;
    float* sden = ws;                                    // N*4
    float* agg  = ws + (size_t)N_NODES * 4;              // N*64
    float* Q    = agg + (size_t)N_NODES * 64;            // N*64
    float* SRC  = Q + (size_t)N_NODES * 64;              // N*192
    float* TW   = SRC + (size_t)N_NODES * 192;           // 3*4096

    float* out_nodes = (float*)d_out;                    // N*64
    float* out_edges = out_nodes + (size_t)N_NODES * 64; // NE*32

    hipMemsetAsync(sden, 0, (size_t)N_NODES * 68 * sizeof(float), stream);

    k_transpose3<<<3, 256, 0, stream>>>(WO, F1, F2, TW);

    k_node_proj<<<(N_NODES + 255) / 256, 256, 0, stream>>>(
        x, WQ, WK, WV, NG, NGb, Q, SRC);

    k_edge_fused<<<1024, 256, 0, stream>>>(
        ea, ei, Q, SRC,
        WE, WEb, EGw, EGb, WOe, WOeb,
        FE1, FE1b, FE2, FE2b,
        n1eg, n1eb, n2eg, n2eb,
        sden, agg, out_edges);

    k_node_final<<<(N_NODES * 64 + 255) / 256, 256, 0, stream>>>(
        agg, sden, x,
        TW, WOb, TW + 4096, F1b, TW + 8192, F2b,
        n1g, n1b, n2g, n2b,
        out_nodes);
}